// Round 7
// baseline (702.844 us; speedup 1.0000x reference)
//
#include <hip/hip_runtime.h>
#include <math.h>

#define BATCH 32
#define NN 1024
#define MM 1024
#define RR 4                    // rows per lane
#define CC 4                    // cols per superstep
#define LANES 64
#define NWAVE 4
#define TPB (MM / 4)            // tile-columns per lane (256)
#define NSUP (TPB + LANES - 1)  // 319 supersteps per wave
#define LAG 72                  // wave lag: 63 lane skew + 9 margin (mult of 8!)
#define TOT8 67                 // ceil((NSUP + 3*LAG)/8) = ceil(535/8)
#define DEPTH 32                // LDS boundary ring depth (float4 entries)
#define WORDS_PER_WAVE 16384    // exact packed diagonal layout (64 KB)
#define DEC_WORDS_PER_BATCH (NWAVE * WORDS_PER_WAVE)          // 65536
#define DEC_BYTES ((size_t)BATCH * DEC_WORDS_PER_BATCH * 4)   // 8 MB
#define REQ_WS DEC_BYTES
#define LPATH (NN + MM - 1)     // 2047

__global__ void init_kernel(float* out) { out[0] = 0.0f; }

// lane i gets lane i-1's value (VALU DPP, no LDS); lane 0 keeps fb.
__device__ __forceinline__ float wave_shr1(float v, float fb) {
    return __int_as_float(__builtin_amdgcn_update_dpp(
        __float_as_int(fb), __float_as_int(v), 0x138, 0xf, 0xf, false));
}

// Packed-diagonal word layout per wave-band: word for (tile-row l, tile-col jc)
// lives at off(d) + l - l0(d), d = jc + l in [0,318], l0(d)=max(0,d-255).
// count(d)=min(d+1,64,319-d... exact): sum = 16384 words per wave.
__device__ __forceinline__ int pkoff(int d) {
    if (d <= 63) return (d * (d + 1)) >> 1;
    if (d <= 256) return 2016 + ((d - 63) << 6);
    const int e = d - 256;
    return 14368 + 63 * e - ((e * (e - 1)) >> 1);
}
__device__ __forceinline__ unsigned ldw(const unsigned* __restrict__ sdec,
                                        int lr, int jc) {
    int d = jc + lr;
    d = d < 0 ? 0 : (d > 318 ? 318 : d);
    const int lo = d > 255 ? d - 255 : 0;
    const int hi = d < 63 ? d : 63;
    const int l = lr < lo ? lo : (lr > hi ? hi : lr);
    return sdec[pkoff(d) + l - lo];
}

// ---- Fused DP + backtrack: 32 blocks (one per batch) x 256 threads ----------
// Wave w owns rows [256w,256w+256); lane l owns rows i0=256w+4l..i0+3 and at
// local superstep ul processes cols j0=4(ul-l)..j0+3. Intra-wave boundary via
// DPP wave_shr:1 (VALU). Cross-wave boundary via 32-deep LDS float4 ring with
// a barrier every 8 iterations (write at X, read at X+8/+9: always >=1
// barrier between). Decision words buffered in registers (8, statically
// indexed) and flushed as coalesced diagonal runs every 8 iterations.
__global__ __launch_bounds__(256, 1) void dtw_fused(
    const float* __restrict__ preds, const float* __restrict__ targs,
    const float* __restrict__ subcoef, unsigned* __restrict__ dec,
    float* __restrict__ out)
{
    const int b = blockIdx.x, t = threadIdx.x;
    const int l = t & 63, w = t >> 6;
    const float INF = __builtin_inff();

    __shared__ float pxA[NN], pyA[NN], txA[MM], tyA[MM];   // 16 KB
    __shared__ float4 ring[NWAVE - 1][DEPTH];              // 1.5 KB
    __shared__ unsigned sdec[WORDS_PER_WAVE];              // 64 KB
    __shared__ unsigned path[LPATH + 1];                   // 8 KB
    __shared__ int sI, sJ, sN;
    __shared__ float wsum[NWAVE];

    for (int it = 0; it < NN / 256; ++it) {
        const int idx = it * 256 + t;
        const float4 p4 = ((const float4*)preds)[(size_t)b * NN + idx];
        pxA[idx] = p4.x; pyA[idx] = p4.y;
        const float4 t4 = ((const float4*)targs)[(size_t)b * MM + idx];
        txA[idx] = t4.x; tyA[idx] = t4.y;
    }
    __syncthreads();

    // ---------------- DP ----------------
    const int i0 = (w << 8) + (l << 2);
    const float4 px4 = ((const float4*)pxA)[i0 >> 2];
    const float4 py4 = ((const float4*)pyA)[i0 >> 2];
    const float px[RR] = {px4.x, px4.y, px4.z, px4.w};
    const float py[RR] = {py4.x, py4.y, py4.z, py4.w};
    unsigned* __restrict__ decW =
        dec + (size_t)b * DEC_WORDS_PER_BATCH + (size_t)w * WORDS_PER_WAVE;

    float Dp[RR], Dbot[CC], bv[CC];
    #pragma unroll
    for (int r = 0; r < RR; ++r) Dp[r] = INF;
    #pragma unroll
    for (int c = 0; c < CC; ++c) { Dbot[c] = INF; bv[c] = INF; }
    // dg for (i0,j0) = previous superstep's bv[3]. Seed: dg=0 at global (0,0)
    // reproduces the reference's inf->0 substitution exactly (argmin=0 too).
    float bndRet = (w == 0 && l == 0) ? 0.0f : INF;
    float4 gcur = make_float4(INF, INF, INF, INF);
    float4 tx4 = ((const float4*)txA)[0], ty4 = ((const float4*)tyA)[0];
    unsigned wreg[8];

    for (int u8 = 0; u8 < TOT8; ++u8) {
        #pragma unroll
        for (int dd = 0; dd < 8; ++dd) {
            const int u = u8 * 8 + dd;
            const int ul = u - LAG * w;          // local superstep
            if (l == 0) {                        // boundary from previous band
                const bool gb = (w > 0) && (ul >= 0) && (ul < TPB);
                bv[0] = gb ? gcur.x : INF; bv[1] = gb ? gcur.y : INF;
                bv[2] = gb ? gcur.z : INF; bv[3] = gb ? gcur.w : INF;
            }
            const bool act = (ul >= l) && (ul < l + TPB);
            if (act) {
                const float cx[CC] = {tx4.x, tx4.y, tx4.z, tx4.w};
                const float cy[CC] = {ty4.x, ty4.y, ty4.z, ty4.w};
                float cost[RR][CC];
                #pragma unroll
                for (int c = 0; c < CC; ++c)
                    #pragma unroll
                    for (int r = 0; r < RR; ++r) {
                        const float dx = px[r] - cx[c], dy = py[r] - cy[c];
                        cost[r][c] = __builtin_amdgcn_sqrtf(dx * dx + dy * dy);
                    }
                unsigned word = 0;
                #pragma unroll
                for (int c = 0; c < CC; ++c) {
                    float up = bv[c];                   // D[i0-1][j0+c]
                    float dg = (c == 0) ? bndRet : bv[c - 1];
                    #pragma unroll
                    for (int r = 0; r < RR; ++r) {
                        const float lf = Dp[r];         // D[i0+r][j0+c-1]
                        const float best = fminf(dg, fminf(up, lf));
                        // == JAX argmin([dg,up,lf]) first-min order:
                        // best==dg <=> dg<=up && dg<=lf; else best==up <=> up<=lf
                        const unsigned m = (best == dg) ? 0u
                                         : ((best == up) ? 1u : 2u);
                        const float D = cost[r][c] + best;
                        word |= m << ((r * 4 + c) * 2);
                        dg = lf; up = D; Dp[r] = D;
                    }
                    Dbot[c] = up;
                }
                wreg[dd] = word;                 // static index (LAG%8==0)
                if (l == LANES - 1 && w < NWAVE - 1)
                    ring[w][ul & (DEPTH - 1)] =
                        make_float4(Dbot[0], Dbot[1], Dbot[2], Dbot[3]);
            }
            // Uniform epilogue: retain dg, DPP boundary pass, prefetch next.
            bndRet = bv[CC - 1];
            #pragma unroll
            for (int c = 0; c < CC; ++c) bv[c] = wave_shr1(Dbot[c], INF);
            const int un = ul + 1;
            if (un >= l && un < l + TPB) {
                const int jn = CC * (un - l);
                tx4 = ((const float4*)txA)[jn >> 2];
                ty4 = ((const float4*)tyA)[jn >> 2];
            }
            if (l == 0 && w > 0 && un >= 0 && un < TPB)
                gcur = ring[w - 1][(un + 63) & (DEPTH - 1)];
        }
        // Coalesced flush: 8 completed diagonals (d = local superstep index).
        const int ulbase = u8 * 8 - LAG * w;
        #pragma unroll
        for (int dd = 0; dd < 8; ++dd) {
            const int d = ulbase + dd;
            if (d >= 0 && d <= 318 && (unsigned)(d - l) < 256u) {
                const int lo = d > 255 ? d - 255 : 0;
                decW[pkoff(d) + l - lo] = wreg[dd];
            }
        }
        __syncthreads();
    }

    __threadfence_block();
    __syncthreads();

    // ---------------- Backtrack: 4 band phases, LDS-staged ----------------
    const unsigned* __restrict__ decB = dec + (size_t)b * DEC_WORDS_PER_BATCH;
    if (t == 0) { sI = NN - 1; sJ = MM - 1; sN = 0; }
    __syncthreads();
    for (int band = NWAVE - 1; band >= 0; --band) {
        {   // stage this band's 64 KB of words (contiguous)
            uint4* s4 = (uint4*)sdec;
            const uint4* g4 = (const uint4*)(decB + band * WORDS_PER_WAVE);
            for (int k = t; k < WORDS_PER_WAVE / 4; k += 256) s4[k] = g4[k];
        }
        __syncthreads();
        if (t == 0 && sI >= (band << 8)) {
            int i = sI, j = sJ, n = sN;
            const int iLow = band << 8, roff = band << 6;
            int lr = (i >> 2) - roff, jc = j >> 2;
            unsigned wcur = ldw(sdec, lr, jc);
            while (true) {
                const unsigned wl = ldw(sdec, lr, jc - 1);
                const unsigned wu = ldw(sdec, lr - 1, jc);
                const unsigned wd = ldw(sdec, lr - 1, jc - 1);
                bool done = false, susp = false;
                while (true) {
                    path[n++] = ((unsigned)i << 16) | (unsigned)j;
                    if ((i | j) == 0) { done = true; break; }
                    const unsigned m =
                        (wcur >> (((i & 3) * 4 + (j & 3)) * 2)) & 3u;
                    i -= (m != 2u); j -= (m != 1u);
                    if (i < iLow) { susp = true; break; }
                    if (((i >> 2) - roff) != lr || (j >> 2) != jc) break;
                }
                if (done || susp) break;
                const int nlr = (i >> 2) - roff, njc = j >> 2;
                wcur = (nlr == lr) ? wl : ((njc == jc) ? wu : wd);
                lr = nlr; jc = njc;
            }
            sI = i; sJ = j; sN = n;
        }
        __syncthreads();
    }

    // ---------------- Parallel loss over the path ----------------
    const float sc0 = subcoef[0], sc1 = subcoef[1];
    const int n = sN;
    float acc = 0.0f;
    for (int p = t; p < n; p += 256) {
        const unsigned e = path[p];
        const int i = (int)(e >> 16), j = (int)(e & 0xffffu);
        acc += fabsf(pxA[i] - txA[j]) * sc0 + fabsf(pyA[i] - tyA[j]) * sc1;
    }
    #pragma unroll
    for (int o = 32; o > 0; o >>= 1) acc += __shfl_down(acc, o);
    if ((t & 63) == 0) wsum[t >> 6] = acc;
    __syncthreads();
    if (t == 0) atomicAdd(out, (wsum[0] + wsum[1]) + (wsum[2] + wsum[3]));
}

// ------------- Fallback (R1 kernel, only if ws too small) --------------------
__global__ __launch_bounds__(256) void dtw_fallback(
    const float* __restrict__ preds, const float* __restrict__ targs,
    const float* __restrict__ subcoef, unsigned* __restrict__ dec,
    float* __restrict__ out)
{
    const int b = blockIdx.x;
    const int t = threadIdx.x;
    const float INF = __builtin_inff();
    __shared__ float px[NN], py[NN];
    __shared__ float txy[2 * MM];
    __shared__ float bbuf[2][256];

    for (int it = 0; it < NN / 256; ++it) {
        const int idx = it * 256 + t;
        const float4 p4 = ((const float4*)preds)[(size_t)b * NN + idx];
        px[idx] = p4.x; py[idx] = p4.y;
        const float4 t4 = ((const float4*)targs)[(size_t)b * MM + idx];
        txy[2 * idx] = t4.x; txy[2 * idx + 1] = t4.y;
    }
    bbuf[0][t] = INF; bbuf[1][t] = INF;
    __syncthreads();

    float pxr[4], pyr[4], Dp[4];
    #pragma unroll
    for (int r = 0; r < 4; ++r) {
        pxr[r] = px[4 * t + r]; pyr[r] = py[4 * t + r]; Dp[r] = INF;
    }
    float dgB = (t == 0) ? 0.0f : INF;
    unsigned packed = 0;
    unsigned* decB = dec + (size_t)b * 65536;
    for (int s = 0; s < MM + 255; ++s) {
        const int j = s - t;
        const float upB = (t == 0) ? INF : bbuf[(s + 1) & 1][t - 1];
        if (j >= 0 && j < MM) {
            const float txj = txy[2 * j], tyj = txy[2 * j + 1];
            float up = upB, dg = dgB;
            unsigned mbits = 0;
            #pragma unroll
            for (int r = 0; r < 4; ++r) {
                const float dx = pxr[r] - txj, dy = pyr[r] - tyj;
                const float c = sqrtf(dx * dx + dy * dy);
                const float lf = Dp[r];
                const unsigned m = (dg <= up && dg <= lf) ? 0u
                                 : ((up <= lf) ? 1u : 2u);
                mbits |= m << (r * 8 + (j & 3) * 2);
                const float Dc = c + fminf(up, fminf(dg, lf));
                dg = lf; up = Dc; Dp[r] = Dc;
            }
            packed |= mbits;
            if ((j & 3) == 3) { decB[(unsigned)t * 256 + (j >> 2)] = packed; packed = 0; }
            bbuf[s & 1][t] = Dp[3];
        }
        dgB = upB;
        __syncthreads();
    }
    __threadfence_block();
    __syncthreads();
    if (t == 0) {
        const float sc0 = subcoef[0], sc1 = subcoef[1];
        int i = NN - 1, jj = MM - 1;
        float loss = 0.0f;
        int ti = i >> 2, tj = jj >> 2;
        unsigned wv = decB[ti * 256 + tj];
        while (true) {
            const int tjl = (tj > 0) ? tj - 1 : 0;
            const int til = (ti > 0) ? ti - 1 : 0;
            const unsigned wl = decB[ti * 256 + tjl];
            const unsigned wu = decB[til * 256 + tj];
            const unsigned wd = decB[til * 256 + tjl];
            bool done = false;
            while (true) {
                loss += fabsf(px[i] - txy[2 * jj]) * sc0
                      + fabsf(py[i] - txy[2 * jj + 1]) * sc1;
                if ((i | jj) == 0) { done = true; break; }
                const unsigned m = (wv >> (((i & 3) * 4 + (jj & 3)) * 2)) & 3u;
                i -= (m != 2u); jj -= (m != 1u);
                if ((i >> 2) != ti || (jj >> 2) != tj) break;
            }
            if (done) break;
            const int nti = i >> 2, ntj = jj >> 2;
            wv = (nti == ti) ? wl : ((ntj == tj) ? wu : wd);
            ti = nti; tj = ntj;
        }
        atomicAdd(out, loss);
    }
}

extern "C" void kernel_launch(void* const* d_in, const int* in_sizes, int n_in,
                              void* d_out, int out_size, void* d_ws, size_t ws_size,
                              hipStream_t stream) {
    const float* preds   = (const float*)d_in[0];
    const float* targs   = (const float*)d_in[1];
    const float* subcoef = (const float*)d_in[2];
    float* out = (float*)d_out;
    unsigned* dec = (unsigned*)d_ws;   // 8 MB

    init_kernel<<<1, 1, 0, stream>>>(out);
    if (ws_size >= REQ_WS) {
        dtw_fused<<<BATCH, 256, 0, stream>>>(preds, targs, subcoef, dec, out);
    } else {
        dtw_fallback<<<BATCH, 256, 0, stream>>>(preds, targs, subcoef, dec, out);
    }
}